// Round 10
// baseline (304.852 us; speedup 1.0000x reference)
//
#include <hip/hip_runtime.h>

#define NN 50000
#define NE 800000
#define RR 8
#define BB 8
#define EPSV 1e-5f
#define SCAN_B ((NN + 255) / 256)   // 196
#define NGRP 64

typedef unsigned short bfu;
typedef signed char i8;
typedef __attribute__((ext_vector_type(8))) short bf16x8;
typedef __attribute__((ext_vector_type(4))) float f32x4;

__device__ inline float bf2f(bfu u) { return __uint_as_float(((unsigned)u) << 16); }
__device__ inline bfu f2bf(float f) {
    unsigned u = __float_as_uint(f);
    return (bfu)((u + 0x7fffu + ((u >> 16) & 1u)) >> 16);   // RTNE
}

#define NW1 36864L
#define NW2 36864L
#define NW3 18432L
#define NZ  (400000L + 50000L + 2L * NGRP * 128)

// ---------------- W packing: logical W[k][o] -> MFMA B-frag layout ----------------
__device__ inline void build_one(const float* __restrict__ comp, const float* __restrict__ bases,
                                 const float* __restrict__ root, bfu* __restrict__ Wp,
                                 int O, int idx) {
    int k = idx / O, o = idx % O;
    float val;
    if (k < 512) {
        int r = k >> 6, i = k & 63;
        val = 0.f;
#pragma unroll
        for (int b = 0; b < BB; ++b)
            val += comp[r * BB + b] * bases[(b * 64 + i) * O + o];
    } else {
        val = root[(k - 512) * O + o];
    }
    int kt = k >> 5, kk = k & 31;
    int lane = ((kk >> 3) << 4) | (o & 15);
    int pos = ((kt * (O / 16) + (o >> 4)) * 64 + lane) * 8 + (kk & 7);
    Wp[pos] = f2bf(val);
}

// ---------------- once: W builds + zero (cnt|fill|stats1|stats2) ----------------
__global__ void prep(const float* __restrict__ c1, const float* __restrict__ b1,
                     const float* __restrict__ r1, bfu* __restrict__ Wp1,
                     const float* __restrict__ c2, const float* __restrict__ b2,
                     const float* __restrict__ r2, bfu* __restrict__ Wp2,
                     const float* __restrict__ c3, const float* __restrict__ b3,
                     const float* __restrict__ r3, bfu* __restrict__ Wp3,
                     float* __restrict__ zbase) {
    long i = (long)blockIdx.x * blockDim.x + threadIdx.x;
    long stride = (long)gridDim.x * blockDim.x;
    const long tot = NW1 + NW2 + NW3 + NZ;
    for (; i < tot; i += stride) {
        if (i < NW1) build_one(c1, b1, r1, Wp1, 64, (int)i);
        else if (i < NW1 + NW2) build_one(c2, b2, r2, Wp2, 64, (int)(i - NW1));
        else if (i < NW1 + NW2 + NW3) build_one(c3, b3, r3, Wp3, 32, (int)(i - NW1 - NW2));
        else zbase[i - (NW1 + NW2 + NW3)] = 0.f;
    }
}

// ---------------- once: x -> xb (bf16) + x8 (int8 row-scaled) + xs (row scale) ----------------
__global__ __launch_bounds__(256) void cvt_rows(const float* __restrict__ x,
                                                bfu* __restrict__ xb,
                                                i8* __restrict__ x8,
                                                float* __restrict__ xs) {
    int wv = threadIdx.x >> 6, lane = threadIdx.x & 63;
    int gw = blockIdx.x * 4 + wv, nw = gridDim.x * 4;
    for (int n = gw; n < NN; n += nw) {
        float v = x[(size_t)n * 64 + lane];
        xb[(size_t)n * 64 + lane] = f2bf(v);
        float am = fabsf(v);
#pragma unroll
        for (int d = 1; d < 64; d <<= 1) am = fmaxf(am, __shfl_xor(am, d));
        am = fmaxf(am, 1e-20f);
        float inv = 127.f / am;
        x8[(size_t)n * 64 + lane] = (i8)__float2int_rn(v * inv);
        if (lane == 0) xs[n] = am * (1.f / 127.f);
    }
}

// ---------------- once: per-(dst,rel) counts, range-binned ----------------
__global__ void edge_count(const int* __restrict__ ei, const int* __restrict__ et,
                           float* __restrict__ cnt) {
    int range = blockIdx.x >> 8;
    int lo = range * (NN / 8), hi = lo + NN / 8;
    int i = (blockIdx.x & 255) * 256 + threadIdx.x;
    for (int e = i; e < NE; e += 256 * 256) {
        int d = ei[NE + e];
        if (d >= lo && d < hi)
            atomicAdd(&cnt[(size_t)d * RR + et[e]], 1.0f);
    }
}

// ---------------- once: exclusive scan of degree -> offs ----------------
__global__ void scan1(const float* __restrict__ cnt, int* __restrict__ offs, int* __restrict__ bsum) {
    __shared__ int sh[256];
    int b = blockIdx.x, t = threadIdx.x;
    int i = b * 256 + t;
    int v = 0;
    if (i < NN) {
        float s = 0.f;
#pragma unroll
        for (int r = 0; r < RR; ++r) s += cnt[(size_t)i * RR + r];
        v = (int)s;
    }
    sh[t] = v;
    __syncthreads();
    for (int s = 1; s < 256; s <<= 1) {
        int tmp = (t >= s) ? sh[t - s] : 0;
        __syncthreads();
        sh[t] += tmp;
        __syncthreads();
    }
    if (i < NN) offs[i] = sh[t] - v;
    if (t == 255) bsum[b] = sh[255];
}

__global__ void scan2(int* __restrict__ bsum, int* __restrict__ offs) {
    if (threadIdx.x == 0 && blockIdx.x == 0) {
        int run = 0;
        for (int b = 0; b < SCAN_B; ++b) { int t = bsum[b]; bsum[b] = run; run += t; }
        offs[NN] = run;
    }
}

__global__ void scan3(int* __restrict__ offs, const int* __restrict__ bsum) {
    int b = blockIdx.x, t = threadIdx.x;
    int i = b * 256 + t;
    if (i < NN) offs[i] += bsum[b];
}

// ---------------- once: place edges dst-sorted, range-binned ----------------
__global__ void place(const int* __restrict__ ei, const int* __restrict__ et,
                      const int* __restrict__ offs, int* __restrict__ fill,
                      unsigned* __restrict__ esrt) {
    int range = blockIdx.x >> 8;
    int lo = range * (NN / 8), hi = lo + NN / 8;
    int i = (blockIdx.x & 255) * 256 + threadIdx.x;
    for (int e = i; e < NE; e += 256 * 256) {
        int d = ei[NE + e];
        if (d >= lo && d < hi) {
            int pos = offs[d] + atomicAdd(&fill[d], 1);
            esrt[pos] = ((unsigned)ei[e] << 3) | (unsigned)et[e];
        }
    }
}

// ---------------- fused per layer: aggregate(int8) -> LDS A-frags -> MFMA GEMM (+BN stats) ----------------
#define ACCUMS(SU, V)                          \
    switch ((SU) & 7) {                        \
        case 0: a0 += (V); break;              \
        case 1: a1 += (V); break;              \
        case 2: a2 += (V); break;              \
        case 3: a3 += (V); break;              \
        case 4: a4 += (V); break;              \
        case 5: a5 += (V); break;              \
        case 6: a6 += (V); break;              \
        default: a7 += (V); break;             \
    }
#define RDL(X, L) __builtin_amdgcn_readlane((int)(X), (L))

// 512 threads = 8 waves; block covers 16 nodes (2 per wave); GEMM by waves 0..CT-1.
template <int O, bool RELU, bool STATS>
__global__ __launch_bounds__(512, 8) void agg_gemm(const int* __restrict__ offs,
                                                   const unsigned* __restrict__ esrt,
                                                   const float* __restrict__ cnt,
                                                   const i8* __restrict__ x8,
                                                   const float* __restrict__ xs,
                                                   const bfu* __restrict__ xb,
                                                   const bfu* __restrict__ Wp,
                                                   const float* __restrict__ bias,
                                                   float* __restrict__ outp,
                                                   float* __restrict__ stats) {
    constexpr int CT = O / 16;
    __shared__ bfu Af[1152 * 8];                     // 18 k-tiles x 64 lanes x 8 bf16 = 18KB
    int wave = threadIdx.x >> 6, lane = threadIdx.x & 63;
    int n0 = blockIdx.x * 16;
    int c = lane;
    int swz_lo = ((c >> 3) & 3) << 4;

#pragma unroll 1
    for (int i = 0; i < 2; ++i) {
        int row = wave * 2 + i;
        int n = n0 + row;
        int j0 = offs[n], j1 = offs[n + 1];
        float a0 = 0.f, a1 = 0.f, a2 = 0.f, a3 = 0.f, a4 = 0.f, a5 = 0.f, a6 = 0.f, a7 = 0.f;
        int j = j0;
        for (; j + 8 <= j1; j += 8) {                // 1 vector load + 8 readlane per batch
            unsigned mye = esrt[j + (lane & 7)];
            int s0 = RDL(mye, 0), s1 = RDL(mye, 1), s2 = RDL(mye, 2), s3 = RDL(mye, 3);
            int s4 = RDL(mye, 4), s5 = RDL(mye, 5), s6 = RDL(mye, 6), s7 = RDL(mye, 7);
            float q0 = (float)x8[(size_t)((unsigned)s0 >> 3) * 64 + lane];
            float q1 = (float)x8[(size_t)((unsigned)s1 >> 3) * 64 + lane];
            float q2 = (float)x8[(size_t)((unsigned)s2 >> 3) * 64 + lane];
            float q3 = (float)x8[(size_t)((unsigned)s3 >> 3) * 64 + lane];
            float q4 = (float)x8[(size_t)((unsigned)s4 >> 3) * 64 + lane];
            float q5 = (float)x8[(size_t)((unsigned)s5 >> 3) * 64 + lane];
            float q6 = (float)x8[(size_t)((unsigned)s6 >> 3) * 64 + lane];
            float q7 = (float)x8[(size_t)((unsigned)s7 >> 3) * 64 + lane];
            float c0 = xs[(unsigned)s0 >> 3], c1 = xs[(unsigned)s1 >> 3];
            float c2 = xs[(unsigned)s2 >> 3], c3 = xs[(unsigned)s3 >> 3];
            float c4 = xs[(unsigned)s4 >> 3], c5 = xs[(unsigned)s5 >> 3];
            float c6 = xs[(unsigned)s6 >> 3], c7 = xs[(unsigned)s7 >> 3];
            ACCUMS(s0, q0 * c0) ACCUMS(s1, q1 * c1) ACCUMS(s2, q2 * c2) ACCUMS(s3, q3 * c3)
            ACCUMS(s4, q4 * c4) ACCUMS(s5, q5 * c5) ACCUMS(s6, q6 * c6) ACCUMS(s7, q7 * c7)
        }
        if (j + 4 <= j1) {
            unsigned mye = esrt[j + (lane & 3)];
            int s0 = RDL(mye, 0), s1 = RDL(mye, 1), s2 = RDL(mye, 2), s3 = RDL(mye, 3);
            float q0 = (float)x8[(size_t)((unsigned)s0 >> 3) * 64 + lane];
            float q1 = (float)x8[(size_t)((unsigned)s1 >> 3) * 64 + lane];
            float q2 = (float)x8[(size_t)((unsigned)s2 >> 3) * 64 + lane];
            float q3 = (float)x8[(size_t)((unsigned)s3 >> 3) * 64 + lane];
            float c0 = xs[(unsigned)s0 >> 3], c1 = xs[(unsigned)s1 >> 3];
            float c2 = xs[(unsigned)s2 >> 3], c3 = xs[(unsigned)s3 >> 3];
            ACCUMS(s0, q0 * c0) ACCUMS(s1, q1 * c1) ACCUMS(s2, q2 * c2) ACCUMS(s3, q3 * c3)
            j += 4;
        }
        for (; j < j1; ++j) {
            int s0 = __builtin_amdgcn_readfirstlane((int)esrt[j]);
            float q0 = (float)x8[(size_t)((unsigned)s0 >> 3) * 64 + lane];
            float c0 = xs[(unsigned)s0 >> 3];
            ACCUMS(s0, q0 * c0)
        }
        // normalize + write A-fragments (granule-XOR-swizzled; verified round 7/8)
#define WR(r, ar) {                                                            \
        float inv = 1.f / fmaxf(cnt[(size_t)n * RR + (r)], 1.f);               \
        bfu bv = f2bf((ar) * inv);                                             \
        int g = (2 * (r) + (c >> 5)) * 64 + (row | swz_lo);                    \
        int gs = g ^ ((g >> 3) & 7) ^ ((g >> 6) & 7);                          \
        Af[gs * 8 + (c & 7)] = bv; }
        WR(0, a0) WR(1, a1) WR(2, a2) WR(3, a3)
        WR(4, a4) WR(5, a5) WR(6, a6) WR(7, a7)
#undef WR
        {   // root-input columns k=512+c (kt = 16,17), full bf16 precision
            bfu bv = xb[(size_t)n * 64 + lane];
            int g = (16 + (c >> 5)) * 64 + (row | swz_lo);
            int gs = g ^ ((g >> 3) & 7) ^ ((g >> 6) & 7);
            Af[gs * 8 + (c & 7)] = bv;
        }
    }
    __syncthreads();

    int ct = wave;
    if (ct < CT) {
        f32x4 acc = (f32x4){0.f, 0.f, 0.f, 0.f};
#pragma unroll
        for (int kt = 0; kt < 18; ++kt) {
            int g = kt * 64 + lane;
            int gs = g ^ ((g >> 3) & 7) ^ ((g >> 6) & 7);
            bf16x8 af = *(const bf16x8*)&Af[gs * 8];
            bf16x8 bfv = *(const bf16x8*)&Wp[((size_t)(kt * CT + ct) * 64 + lane) * 8];
            acc = __builtin_amdgcn_mfma_f32_16x16x32_bf16(af, bfv, acc, 0, 0, 0);
        }
        int col = ct * 16 + (lane & 15);
        float b = bias[col];
        float ssum = 0.f, sq = 0.f;
#pragma unroll
        for (int jj = 0; jj < 4; ++jj) {
            int row = (lane >> 4) * 4 + jj;
            float v = acc[jj] + b;
            if (RELU) v = fmaxf(v, 0.f);
            outp[(size_t)(n0 + row) * O + col] = v;
            if (STATS) { ssum += v; sq += v * v; }
        }
        if (STATS) {
            ssum += __shfl_xor(ssum, 16); ssum += __shfl_xor(ssum, 32);
            sq   += __shfl_xor(sq, 16);   sq   += __shfl_xor(sq, 32);
            if ((lane >> 4) == 0) {
                int g = blockIdx.x & (NGRP - 1);
                atomicAdd(&stats[g * 128 + col], ssum);
                atomicAdd(&stats[g * 128 + 64 + col], sq);
            }
        }
    }
}

// ---------------- BN: finalize + apply; emits bf16 + row-scaled int8 ----------------
template <bool HASRES>
__global__ __launch_bounds__(256) void bn_apply(const float* __restrict__ y,
                                                const float* __restrict__ stats,
                                                const float* __restrict__ gamma,
                                                const float* __restrict__ beta,
                                                const bfu* __restrict__ resb,
                                                bfu* __restrict__ hb,
                                                i8* __restrict__ h8,
                                                float* __restrict__ hs) {
    __shared__ float sc[128];
    int t = threadIdx.x;
    if (t < 64) {
        float s = 0.f, q = 0.f;
        for (int g = 0; g < NGRP; ++g) {
            s += stats[g * 128 + t];
            q += stats[g * 128 + 64 + t];
        }
        float mu = s / (float)NN;
        float var = q / (float)NN - mu * mu;
        float scale = gamma[t] * rsqrtf(var + EPSV);
        sc[t] = scale;
        sc[64 + t] = beta[t] - mu * scale;
    }
    __syncthreads();
    int wv = threadIdx.x >> 6, lane = threadIdx.x & 63;
    int gw = blockIdx.x * 4 + wv, nw = gridDim.x * 4;
    for (int n = gw; n < NN; n += nw) {
        float v = y[(size_t)n * 64 + lane] * sc[lane] + sc[64 + lane];
        if (HASRES) v += bf2f(resb[(size_t)n * 64 + lane]);
        hb[(size_t)n * 64 + lane] = f2bf(v);
        float am = fabsf(v);
#pragma unroll
        for (int d = 1; d < 64; d <<= 1) am = fmaxf(am, __shfl_xor(am, d));
        am = fmaxf(am, 1e-20f);
        float inv = 127.f / am;
        h8[(size_t)n * 64 + lane] = (i8)__float2int_rn(v * inv);
        if (lane == 0) hs[n] = am * (1.f / 127.f);
    }
}

extern "C" void kernel_launch(void* const* d_in, const int* in_sizes, int n_in,
                              void* d_out, int out_size, void* d_ws, size_t ws_size,
                              hipStream_t stream) {
    const float* x      = (const float*)d_in[0];
    const int*   ei     = (const int*)d_in[1];
    const int*   et     = (const int*)d_in[2];
    const float* comp1  = (const float*)d_in[3];
    const float* bases1 = (const float*)d_in[4];
    const float* root1  = (const float*)d_in[5];
    const float* bias1  = (const float*)d_in[6];
    const float* comp2  = (const float*)d_in[7];
    const float* bases2 = (const float*)d_in[8];
    const float* root2  = (const float*)d_in[9];
    const float* bias2  = (const float*)d_in[10];
    const float* comp3  = (const float*)d_in[11];
    const float* bases3 = (const float*)d_in[12];
    const float* root3  = (const float*)d_in[13];
    const float* bias3  = (const float*)d_in[14];
    const float* gamma1 = (const float*)d_in[15];
    const float* beta1  = (const float*)d_in[16];
    const float* gamma2 = (const float*)d_in[17];
    const float* beta2  = (const float*)d_in[18];
    float* out = (float*)d_out;

    float* ws = (float*)d_ws;
    size_t off = 0;
    bfu* Wp1 = (bfu*)(ws + off); off += 18432;                // 36864 bf16
    bfu* Wp2 = (bfu*)(ws + off); off += 18432;
    bfu* Wp3 = (bfu*)(ws + off); off += 9216;                 // 18432 bf16
    float* cnt    = ws + off; off += (size_t)NN * RR;         // -- zero region start
    int*   fill   = (int*)(ws + off); off += NN;
    float* stats1 = ws + off; off += NGRP * 128;
    float* stats2 = ws + off; off += NGRP * 128;              // -- zero region end
    float* y  = ws + off; off += (size_t)NN * 64;
    bfu* xb   = (bfu*)(ws + off); off += (size_t)NN * 32;
    bfu* h1b  = (bfu*)(ws + off); off += (size_t)NN * 32;
    bfu* hb   = (bfu*)(ws + off); off += (size_t)NN * 32;
    i8*  x8   = (i8*)(ws + off);  off += (size_t)NN * 16;
    i8*  h1_8 = (i8*)(ws + off);  off += (size_t)NN * 16;
    i8*  h_8  = (i8*)(ws + off);  off += (size_t)NN * 16;
    float* xsc  = ws + off; off += NN;
    float* h1sc = ws + off; off += NN;
    float* hsc  = ws + off; off += NN;
    int* offs = (int*)(ws + off); off += NN + 4;
    int* bsum = (int*)(ws + off); off += 256;
    unsigned* esrt = (unsigned*)(ws + off); off += NE;

    // ---- once: prep (W pack + zeros), cvt, counts, CSR ----
    prep<<<dim3(1024), dim3(256), 0, stream>>>(comp1, bases1, root1, Wp1,
                                               comp2, bases2, root2, Wp2,
                                               comp3, bases3, root3, Wp3, cnt);
    cvt_rows<<<dim3(512), dim3(256), 0, stream>>>(x, xb, x8, xsc);
    edge_count<<<dim3(2048), dim3(256), 0, stream>>>(ei, et, cnt);
    scan1<<<dim3(SCAN_B), dim3(256), 0, stream>>>(cnt, offs, bsum);
    scan2<<<dim3(1), dim3(64), 0, stream>>>(bsum, offs);
    scan3<<<dim3(SCAN_B), dim3(256), 0, stream>>>(offs, bsum);
    place<<<dim3(2048), dim3(256), 0, stream>>>(ei, et, offs, fill, esrt);

    // ---- layer 1 ----
    agg_gemm<64, true, true><<<dim3(NN / 16), dim3(512), 0, stream>>>(offs, esrt, cnt, x8, xsc, xb, Wp1, bias1, y, stats1);
    bn_apply<false><<<dim3(1024), dim3(256), 0, stream>>>(y, stats1, gamma1, beta1, nullptr, h1b, h1_8, h1sc);

    // ---- layer 2 ----
    agg_gemm<64, true, true><<<dim3(NN / 16), dim3(512), 0, stream>>>(offs, esrt, cnt, h1_8, h1sc, h1b, Wp2, bias2, y, stats2);
    bn_apply<true><<<dim3(1024), dim3(256), 0, stream>>>(y, stats2, gamma2, beta2, h1b, hb, h_8, hsc);

    // ---- layer 3 (output) ----
    agg_gemm<32, false, false><<<dim3(NN / 16), dim3(512), 0, stream>>>(offs, esrt, cnt, h_8, hsc, hb, Wp3, bias3, out, nullptr);
}